// Round 5
// baseline (552.449 us; speedup 1.0000x reference)
//
#include <hip/hip_runtime.h>
#include <hip/hip_cooperative_groups.h>
#include <stdint.h>

namespace cg = cooperative_groups;

#define NN   4096
#define NE   131072
#define KIN  512
#define NH   8
#define HF   256
#define SLOPE 0.2f
#define NBLK 1024
#define NTHR 256

typedef __attribute__((ext_vector_type(8))) short bf16x8;
typedef __attribute__((ext_vector_type(4))) float f32x4;

// ws layout: [0,2MB) bitmap | [2,4MB) gbf | [4MB,+128K) el | +128K er | [4.25MB,+4MB) Abf | [8.25MB,+256K) Btbf

__device__ __forceinline__ unsigned short f2bf(float x) {  // RTN f32->bf16
  unsigned u = __builtin_bit_cast(unsigned, x);
  u += 0x7FFFu + ((u >> 16) & 1u);
  return (unsigned short)(u >> 16);
}
__device__ __forceinline__ float bf2f(unsigned short x) {
  unsigned u = ((unsigned)x) << 16;
  return __builtin_bit_cast(float, u);
}

__global__ __launch_bounds__(256, 4) void fused_k(
    const float* __restrict__ h, const int* __restrict__ ei, const float* __restrict__ mask,
    const float* __restrict__ Wfc, const float* __restrict__ Wa, float* __restrict__ out,
    unsigned* __restrict__ bitmap, unsigned short* __restrict__ Abf,
    unsigned short* __restrict__ Btbf, unsigned short* __restrict__ gbf,
    float* __restrict__ el, float* __restrict__ er) {
  __shared__ char ldsraw[16384];   // union: gemm dbuf 16KB / transpose tile 4.2KB / jl 8KB / red 512B
  __shared__ int wtot[4];
  __shared__ int totalS;
  cg::grid_group grid = cg::this_grid();
  const int bid = blockIdx.x, t = threadIdx.x;
  const int gtid = bid * NTHR + t;

  // ================= P0: clear bitmap + convert A + convert B^T =================
  if (gtid < 131072) ((float4*)bitmap)[gtid] = make_float4(0.f, 0.f, 0.f, 0.f);
  {
    const float4* A4 = (const float4*)h;     // 524288 quads, exactly 2/thread
#pragma unroll
    for (int rep = 0; rep < 2; ++rep) {
      int q = gtid + rep * (NBLK * NTHR);
      float4 v = A4[q];
      ushort4 o; o.x = f2bf(v.x); o.y = f2bf(v.y); o.z = f2bf(v.z); o.w = f2bf(v.w);
      ((ushort4*)Abf)[q] = o;
    }
  }
  if (bid < 128) {                            // W_fc [512][256] -> Bt [256][512] bf16
    float* tile = (float*)ldsraw;             // [32][33]
    int k0 = (bid >> 3) * 32, n0 = (bid & 7) * 32;
    int lr = t >> 3, lc = (t & 7) * 4;
    float4 v = *(const float4*)&Wfc[(size_t)(k0 + lr) * HF + n0 + lc];
    tile[lr * 33 + lc] = v.x; tile[lr * 33 + lc + 1] = v.y;
    tile[lr * 33 + lc + 2] = v.z; tile[lr * 33 + lc + 3] = v.w;
    __syncthreads();
    ushort4 o;
    o.x = f2bf(tile[(lc + 0) * 33 + lr]); o.y = f2bf(tile[(lc + 1) * 33 + lr]);
    o.z = f2bf(tile[(lc + 2) * 33 + lr]); o.w = f2bf(tile[(lc + 3) * 33 + lr]);
    *(ushort4*)&Btbf[(size_t)(n0 + lr) * KIN + k0 + lc] = o;
  }
  __threadfence();   // agent-scope: write back dirty L2 (cross-XCD, G16)
  grid.sync();
  __threadfence();

  // ================= P1: adj atomics + 32x32-tile MFMA GEMM + el/er epilogue ====
  if (bid < 528) {                            // NE+NN = 135168 = 528*256 exactly
    int k = bid * NTHR + t;
    int s, d; float m;
    if (k < NE) { s = ei[k]; d = ei[NE + k]; m = mask[k]; }
    else        { s = k - NE; d = s; m = 1.0f; }
    if (m != 0.0f) atomicOr(&bitmap[s * 128 + (d >> 5)], 1u << (d & 31));
  }
  {
    unsigned short* smem = (unsigned short*)ldsraw;  // [2][4096]: A[32][64]@0, B[32][64]@2048
    const int gx = bid & 127, gy = bid >> 7;         // 128 M-tiles x 8 N-tiles(=heads)
    const int row0 = gx * 32, col0 = gy * 32;
    const int w = t >> 6, l = t & 63;
    const int wr = w >> 1, wc = w & 1;
    const int srow = (w << 3) + (l >> 3);            // wave w stages rows w*8..+8 of A and B
    const int sch  = (l & 7) ^ (srow & 7);           // pre-swizzled source (rule #21)
    const unsigned short* gA = &Abf[(size_t)(row0 + srow) * KIN + sch * 8];
    const unsigned short* gB = &Btbf[(size_t)(col0 + srow) * KIN + sch * 8];

#define STAGE(bf, ks)                                                                             \
  do {                                                                                            \
    __builtin_amdgcn_global_load_lds(                                                             \
        (const __attribute__((address_space(1))) unsigned int*)(gA + (size_t)(ks) * 64),          \
        (__attribute__((address_space(3))) unsigned int*)(&smem[(bf) * 4096 + w * 512]), 16, 0, 0);\
    __builtin_amdgcn_global_load_lds(                                                             \
        (const __attribute__((address_space(1))) unsigned int*)(gB + (size_t)(ks) * 64),          \
        (__attribute__((address_space(3))) unsigned int*)(&smem[(bf) * 4096 + 2048 + w * 512]),   \
        16, 0, 0);                                                                                \
  } while (0)

    f32x4 acc = {};
    STAGE(0, 0);
    __syncthreads();
    const int lrow = l & 15, kg = l >> 4;
    const int ar = wr * 16 + lrow, br = wc * 16 + lrow;
    for (int ks = 0; ks < 8; ++ks) {
      const int bf = ks & 1;
      if (ks < 7) STAGE(bf ^ 1, ks + 1);
      bf16x8 a0 = *(const bf16x8*)&smem[bf * 4096 + ar * 64 + ((kg ^ (ar & 7)) << 3)];
      bf16x8 a1 = *(const bf16x8*)&smem[bf * 4096 + ar * 64 + (((4 + kg) ^ (ar & 7)) << 3)];
      bf16x8 b0 = *(const bf16x8*)&smem[bf * 4096 + 2048 + br * 64 + ((kg ^ (br & 7)) << 3)];
      bf16x8 b1 = *(const bf16x8*)&smem[bf * 4096 + 2048 + br * 64 + (((4 + kg) ^ (br & 7)) << 3)];
      acc = __builtin_amdgcn_mfma_f32_16x16x32_bf16(a0, b0, acc, 0, 0, 0);
      acc = __builtin_amdgcn_mfma_f32_16x16x32_bf16(a1, b1, acc, 0, 0, 0);
      __syncthreads();
    }
#undef STAGE

    // C/D: col=lane&15, row=(lane>>4)*4+q  [m89-verified]
    const int crow = (l >> 4) * 4, ccol = l & 15;
    const int gr0 = row0 + wr * 16 + crow, gc = col0 + wc * 16 + ccol;
#pragma unroll
    for (int q = 0; q < 4; ++q) gbf[(size_t)(gr0 + q) * HF + gc] = f2bf(acc[q]);

    // fused el/er: this block's 32 cols == head gy's full f range
    float* red = (float*)ldsraw;               // [128] floats, reuse after final K-loop sync
    const int f = wc * 16 + ccol;
    const float wal = Wa[f], war = Wa[32 + f];
#pragma unroll
    for (int q = 0; q < 4; ++q) {
      float pel = acc[q] * wal, per = acc[q] * war;
#pragma unroll
      for (int m = 8; m >= 1; m >>= 1) { pel += __shfl_xor(pel, m); per += __shfl_xor(per, m); }
      if (ccol == 0) {
        int rl = wr * 16 + crow + q;
        red[wc * 32 + rl] = pel;
        red[64 + wc * 32 + rl] = per;
      }
    }
    __syncthreads();
    if (t < 32) {
      el[(row0 + t) * NH + gy] = red[t] + red[32 + t];
      er[(row0 + t) * NH + gy] = red[64 + t] + red[96 + t];
    }
  }
  __threadfence();
  grid.sync();
  __threadfence();

  // ================= P2: attn, rows bid, bid+1024, bid+2048, bid+3072 ==========
  unsigned short* jl = (unsigned short*)ldsraw;
  const int lane = t & 63;
  for (int rr = 0; rr < 4; ++rr) {
    const int i = bid + rr * NBLK;
    __syncthreads();                           // jl/wtot reuse boundary
    unsigned wbits = 0; int cnt = 0;
    if (t < 128) { wbits = bitmap[i * 128 + t]; cnt = __popc(wbits); }
    int incl = cnt;
#pragma unroll
    for (int d2 = 1; d2 < 64; d2 <<= 1) {
      int u = __shfl_up(incl, d2);
      if (lane >= d2) incl += u;
    }
    if (lane == 63) wtot[t >> 6] = incl;
    __syncthreads();
    int base2 = (t >= 64 && t < 128) ? wtot[0] : 0;
    if (t == 127) totalS = base2 + incl;
    if (t < 128) {
      int off = base2 + incl - cnt;
      unsigned ww = wbits;
      while (ww) {
        int b = __ffs(ww) - 1;
        jl[off++] = (unsigned short)(t * 32 + b);
        ww &= ww - 1;
      }
    }
    __syncthreads();
    const int total = totalS;
    const int hh = t >> 5;
    const float elh = el[i * NH + hh];
    float acc0 = 0.f, den0 = 0.f, acc1 = 0.f, den1 = 0.f;
    int k = 0;
    for (; k + 2 <= total; k += 2) {
      int j0 = jl[k], j1 = jl[k + 1];
      float e0 = elh + er[(size_t)j0 * NH + hh];
      float e1 = elh + er[(size_t)j1 * NH + hh];
      float g0 = bf2f(gbf[(size_t)j0 * HF + t]);
      float g1 = bf2f(gbf[(size_t)j1 * HF + t]);
      float l0 = e0 > 0.f ? e0 : SLOPE * e0;
      float l1 = e1 > 0.f ? e1 : SLOPE * e1;
      float w0 = __expf(l0), w1 = __expf(l1);
      den0 += w0; den1 += w1;
      acc0 += w0 * g0; acc1 += w1 * g1;
    }
    if (k < total) {
      int j0 = jl[k];
      float e0 = elh + er[(size_t)j0 * NH + hh];
      float g0 = bf2f(gbf[(size_t)j0 * HF + t]);
      float l0 = e0 > 0.f ? e0 : SLOPE * e0;
      float w0 = __expf(l0);
      den0 += w0; acc0 += w0 * g0;
    }
    out[(size_t)i * HF + t] = (acc0 + acc1) / (den0 + den1);
  }
}

extern "C" void kernel_launch(void* const* d_in, const int* in_sizes, int n_in,
                              void* d_out, int out_size, void* d_ws, size_t ws_size,
                              hipStream_t stream) {
  const float* h      = (const float*)d_in[0];
  const int*   ei     = (const int*)d_in[1];
  const float* mask   = (const float*)d_in[2];
  const float* W_fc   = (const float*)d_in[3];
  const float* W_attn = (const float*)d_in[4];
  float* out = (float*)d_out;

  char* ws = (char*)d_ws;
  unsigned* bitmap      = (unsigned*)ws;                                          // 2 MB
  unsigned short* gbf   = (unsigned short*)(ws + (size_t)2 * 1024 * 1024);        // 2 MB
  float* el             = (float*)(ws + (size_t)4 * 1024 * 1024);                 // 128 KB
  float* er             = (float*)(ws + (size_t)4 * 1024 * 1024 + 128 * 1024);    // 128 KB
  unsigned short* Abf   = (unsigned short*)(ws + (size_t)4 * 1024 * 1024 + 256 * 1024);  // 4 MB
  unsigned short* Btbf  = (unsigned short*)(ws + (size_t)8 * 1024 * 1024 + 256 * 1024);  // 256 KB

  void* args[] = {(void*)&h, (void*)&ei, (void*)&mask, (void*)&W_fc, (void*)&W_attn,
                  (void*)&out, (void*)&bitmap, (void*)&Abf, (void*)&Btbf, (void*)&gbf,
                  (void*)&el, (void*)&er};
  hipLaunchCooperativeKernel((void*)fused_k, dim3(NBLK), dim3(NTHR), args, 0, stream);
}

// Round 6
// 37.028 us; speedup vs baseline: 14.9198x; 14.9198x over previous
//
#include <hip/hip_runtime.h>
#include <stdint.h>

#define NN   4096
#define NE   131072
#define KIN  512
#define NH   8
#define HF   256
#define SLOPE 0.2f

typedef __attribute__((ext_vector_type(8))) short bf16x8;
typedef __attribute__((ext_vector_type(4))) float f32x4;

// ws layout: [0,2MB) bitmap | [2,4MB) gbf bf16 | [4MB,+128K) el | +128K er |
//            [4.25MB,+4MB) Abf | [8.25MB,+256K) Btbf (W_fc^T bf16)

__device__ __forceinline__ unsigned short f2bf(float x) {  // RTN f32->bf16
  unsigned u = __builtin_bit_cast(unsigned, x);
  u += 0x7FFFu + ((u >> 16) & 1u);
  return (unsigned short)(u >> 16);
}
__device__ __forceinline__ float bf2f(unsigned short x) {
  unsigned u = ((unsigned)x) << 16;
  return __builtin_bit_cast(float, u);
}

// K1: blocks 0..511 clear bitmap; 512..2559 h->bf16; 2560..2687 W_fc->B^T bf16
__global__ __launch_bounds__(256) void prep_k(const float* __restrict__ A,
                                              const float* __restrict__ B,
                                              unsigned* __restrict__ bitmap,
                                              unsigned short* __restrict__ Abf,
                                              unsigned short* __restrict__ Btbf) {
  __shared__ float tile[32][33];
  const int b = blockIdx.x, t = threadIdx.x;
  if (b < 512) {
    ((float4*)bitmap)[b * 256 + t] = make_float4(0.f, 0.f, 0.f, 0.f);
  } else if (b < 2560) {
    size_t idx = ((size_t)(b - 512) * 256 + t) * 4;
    float4 v = *(const float4*)&A[idx];
    ushort4 o;
    o.x = f2bf(v.x); o.y = f2bf(v.y); o.z = f2bf(v.z); o.w = f2bf(v.w);
    *(ushort4*)&Abf[idx] = o;
  } else {
    int bb = b - 2560;
    int k0 = (bb >> 3) * 32, n0 = (bb & 7) * 32;
    int lr = t >> 3, lc = (t & 7) * 4;
    float4 v = *(const float4*)&B[(size_t)(k0 + lr) * HF + n0 + lc];
    tile[lr][lc] = v.x; tile[lr][lc + 1] = v.y; tile[lr][lc + 2] = v.z; tile[lr][lc + 3] = v.w;
    __syncthreads();
    ushort4 o;
    o.x = f2bf(tile[lc + 0][lr]); o.y = f2bf(tile[lc + 1][lr]);
    o.z = f2bf(tile[lc + 2][lr]); o.w = f2bf(tile[lc + 3][lr]);
    *(ushort4*)&Btbf[(size_t)(n0 + lr) * KIN + k0 + lc] = o;
  }
}

// K2: blocks 0..1023 = 32x32 MFMA GEMM tiles (128 M x 8 heads), BK=64, dbuf,
//     fused el/er epilogue; blocks 1024..1551 = build_adj.
__global__ __launch_bounds__(256) void gemm_adj_k(const unsigned short* __restrict__ A,
                                                  const unsigned short* __restrict__ Bt,
                                                  const float* __restrict__ Wa,
                                                  unsigned short* __restrict__ gbf,
                                                  float* __restrict__ el,
                                                  float* __restrict__ er,
                                                  const int* __restrict__ ei,
                                                  const float* __restrict__ mask,
                                                  unsigned* __restrict__ bitmap) {
  __shared__ unsigned short smem[2][4096];  // per buf: A[32][64]@0, B[32][64]@2048
  const int bx = blockIdx.x, t = threadIdx.x;
  if (bx >= 1024) {  // ---- build_adj: NE+NN = 135168 = 528*256 exactly ----
    int k = (bx - 1024) * 256 + t;
    int s, d; float m;
    if (k < NE) { s = ei[k]; d = ei[NE + k]; m = mask[k]; }
    else        { s = k - NE; d = s; m = 1.0f; }   // diagonal forced to 1
    if (m != 0.0f) atomicOr(&bitmap[s * 128 + (d >> 5)], 1u << (d & 31));
    return;
  }
  // ---- gemm: 32x32 tile, gy selects the head ----
  const int gx = bx & 127, gy = bx >> 7;
  const int row0 = gx * 32, col0 = gy * 32;
  const int w = t >> 6, l = t & 63;
  const int wr = w >> 1, wc = w & 1;

  // staging: linear LDS dest; source k-chunk pre-swizzled (rule #21)
  const int srow = (w << 3) + (l >> 3);            // wave w stages rows 8w..8w+7
  const int sch  = (l & 7) ^ (srow & 7);
  const unsigned short* gA = &A[(size_t)(row0 + srow) * KIN + sch * 8];
  const unsigned short* gB = &Bt[(size_t)(col0 + srow) * KIN + sch * 8];

#define STAGE(bf, ks)                                                                             \
  do {                                                                                            \
    __builtin_amdgcn_global_load_lds(                                                             \
        (const __attribute__((address_space(1))) unsigned int*)(gA + (size_t)(ks) * 64),          \
        (__attribute__((address_space(3))) unsigned int*)(&smem[bf][w * 512]), 16, 0, 0);         \
    __builtin_amdgcn_global_load_lds(                                                             \
        (const __attribute__((address_space(1))) unsigned int*)(gB + (size_t)(ks) * 64),          \
        (__attribute__((address_space(3))) unsigned int*)(&smem[bf][2048 + w * 512]), 16, 0, 0);  \
  } while (0)

  f32x4 acc = {};
  STAGE(0, 0);
  __syncthreads();
  const int lrow = l & 15, kg = l >> 4;
  const int ar = wr * 16 + lrow, br = wc * 16 + lrow;
  for (int ks = 0; ks < 8; ++ks) {
    const int bf = ks & 1;
    if (ks < 7) STAGE(bf ^ 1, ks + 1);
    bf16x8 a0 = *(const bf16x8*)&smem[bf][ar * 64 + ((kg ^ (ar & 7)) << 3)];
    bf16x8 a1 = *(const bf16x8*)&smem[bf][ar * 64 + (((4 + kg) ^ (ar & 7)) << 3)];
    bf16x8 b0 = *(const bf16x8*)&smem[bf][2048 + br * 64 + ((kg ^ (br & 7)) << 3)];
    bf16x8 b1 = *(const bf16x8*)&smem[bf][2048 + br * 64 + (((4 + kg) ^ (br & 7)) << 3)];
    acc = __builtin_amdgcn_mfma_f32_16x16x32_bf16(a0, b0, acc, 0, 0, 0);
    acc = __builtin_amdgcn_mfma_f32_16x16x32_bf16(a1, b1, acc, 0, 0, 0);
    __syncthreads();
  }
#undef STAGE

  // C/D: col=lane&15, row=(lane>>4)*4+q  [m89-verified]
  const int crow = (l >> 4) * 4, ccol = l & 15;
  const int gr0 = row0 + wr * 16 + crow, gc = col0 + wc * 16 + ccol;
#pragma unroll
  for (int q = 0; q < 4; ++q) gbf[(size_t)(gr0 + q) * HF + gc] = f2bf(acc[q]);

  // fused el/er: this block's 32 cols == head gy's full f range
  float* red = (float*)smem;                 // reuse after final K-loop sync
  const int f = wc * 16 + ccol;
  const float wal = Wa[f], war = Wa[32 + f];
#pragma unroll
  for (int q = 0; q < 4; ++q) {
    float pel = acc[q] * wal, per = acc[q] * war;
#pragma unroll
    for (int m = 8; m >= 1; m >>= 1) { pel += __shfl_xor(pel, m); per += __shfl_xor(per, m); }
    if (ccol == 0) {
      int rl = wr * 16 + crow + q;
      red[wc * 32 + rl] = pel;
      red[64 + wc * 32 + rl] = per;
    }
  }
  __syncthreads();
  if (t < 32) {
    el[(row0 + t) * NH + gy] = red[t] + red[32 + t];
    er[(row0 + t) * NH + gy] = red[64 + t] + red[96 + t];
  }
}

// K3: one block per row i; thread t owns output element (h=t>>5, f=t&31).
// Two-phase per 256-neighbor chunk: A) parallel exp table into LDS,
// B) 4-way unrolled accumulate (only global access = independent gbf rows).
__global__ __launch_bounds__(256) void attn_k(const unsigned* __restrict__ bitmap,
                                              const unsigned short* __restrict__ gbf,
                                              const float* __restrict__ el_,
                                              const float* __restrict__ er_,
                                              float* __restrict__ out) {
  __shared__ unsigned short jl[NN];        // 8KB
  __shared__ float wlds[256 * NH];         // 8KB exp table per chunk
  __shared__ int wtot[4];
  __shared__ int totalS;

  const int i = blockIdx.x;
  const int t = threadIdx.x;
  const int lane = t & 63;

  // expand bitmap row -> sorted neighbor list (deterministic)
  unsigned wbits = 0; int cnt = 0;
  if (t < 128) { wbits = bitmap[i * 128 + t]; cnt = __popc(wbits); }
  int incl = cnt;
#pragma unroll
  for (int d = 1; d < 64; d <<= 1) {
    int u = __shfl_up(incl, d);
    if (lane >= d) incl += u;
  }
  if (lane == 63) wtot[t >> 6] = incl;
  __syncthreads();
  int base = (t >= 64 && t < 128) ? wtot[0] : 0;
  if (t == 127) totalS = base + incl;
  if (t < 128) {
    int off = base + incl - cnt;
    unsigned ww = wbits;
    while (ww) {
      int b = __ffs(ww) - 1;
      jl[off++] = (unsigned short)(t * 32 + b);
      ww &= ww - 1;
    }
  }
  __syncthreads();
  const int total = totalS;

  const int hh = t >> 5;
  float acc = 0.f, den = 0.f;
  for (int c0 = 0; c0 < total; c0 += 256) {
    const int CL = min(256, total - c0);
    // phase A: all exps in parallel (no max-subtraction: |e| small, f32-safe)
    for (int p = t; p < CL * NH; p += 256) {
      int k = p >> 3, h2 = p & 7;
      int j = jl[c0 + k];
      float e  = el_[i * NH + h2] + er_[(size_t)j * NH + h2];
      float lr = e > 0.f ? e : SLOPE * e;
      wlds[p] = __expf(lr);
    }
    __syncthreads();
    // phase B: streaming accumulate, 4-way unrolled
    int k = 0;
    for (; k + 4 <= CL; k += 4) {
      int j0 = jl[c0 + k], j1 = jl[c0 + k + 1], j2 = jl[c0 + k + 2], j3 = jl[c0 + k + 3];
      float g0 = bf2f(gbf[(size_t)j0 * HF + t]);
      float g1 = bf2f(gbf[(size_t)j1 * HF + t]);
      float g2 = bf2f(gbf[(size_t)j2 * HF + t]);
      float g3 = bf2f(gbf[(size_t)j3 * HF + t]);
      float w0 = wlds[(k + 0) * NH + hh], w1 = wlds[(k + 1) * NH + hh];
      float w2 = wlds[(k + 2) * NH + hh], w3 = wlds[(k + 3) * NH + hh];
      den += (w0 + w1) + (w2 + w3);
      acc += w0 * g0; acc += w1 * g1; acc += w2 * g2; acc += w3 * g3;
    }
    for (; k < CL; ++k) {
      int j0 = jl[c0 + k];
      float w0 = wlds[k * NH + hh];
      den += w0;
      acc += w0 * bf2f(gbf[(size_t)j0 * HF + t]);
    }
    __syncthreads();   // wlds reuse boundary
  }
  out[(size_t)i * HF + t] = acc / den;
}

extern "C" void kernel_launch(void* const* d_in, const int* in_sizes, int n_in,
                              void* d_out, int out_size, void* d_ws, size_t ws_size,
                              hipStream_t stream) {
  const float* h      = (const float*)d_in[0];
  const int*   ei     = (const int*)d_in[1];
  const float* mask   = (const float*)d_in[2];
  const float* W_fc   = (const float*)d_in[3];
  const float* W_attn = (const float*)d_in[4];
  float* out = (float*)d_out;

  char* ws = (char*)d_ws;
  unsigned* bitmap      = (unsigned*)ws;                                          // 2 MB
  unsigned short* gbf   = (unsigned short*)(ws + (size_t)2 * 1024 * 1024);        // 2 MB
  float* el             = (float*)(ws + (size_t)4 * 1024 * 1024);                 // 128 KB
  float* er             = (float*)(ws + (size_t)4 * 1024 * 1024 + 128 * 1024);    // 128 KB
  unsigned short* Abf   = (unsigned short*)(ws + (size_t)4 * 1024 * 1024 + 256 * 1024);  // 4 MB
  unsigned short* Btbf  = (unsigned short*)(ws + (size_t)8 * 1024 * 1024 + 256 * 1024);  // 256 KB

  prep_k<<<2688, 256, 0, stream>>>(h, W_fc, bitmap, Abf, Btbf);
  gemm_adj_k<<<1024 + 528, 256, 0, stream>>>(Abf, Btbf, W_attn, gbf, el, er, ei, mask, bitmap);
  attn_k<<<NN, 256, 0, stream>>>(bitmap, gbf, el, er, out);
}

// Round 7
// 34.962 us; speedup vs baseline: 15.8016x; 1.0591x over previous
//
#include <hip/hip_runtime.h>
#include <stdint.h>

#define NN   4096
#define NE   131072
#define KIN  512
#define NH   8
#define HF   256
#define SLOPE 0.2f

typedef __attribute__((ext_vector_type(8))) short bf16x8;
typedef __attribute__((ext_vector_type(4))) float f32x4;

// ws layout: [0,2MB) bitmap | [2,4MB) gbf bf16 | [4MB,+128K) el | +128K er |
//            [4.25MB,+256K) Btbf (W_fc^T bf16)

__device__ __forceinline__ unsigned short f2bf(float x) {  // RTN-even f32->bf16
  unsigned u = __builtin_bit_cast(unsigned, x);
  u += 0x7FFFu + ((u >> 16) & 1u);
  return (unsigned short)(u >> 16);
}
__device__ __forceinline__ float bf2f(unsigned short x) {
  unsigned u = ((unsigned)x) << 16;
  return __builtin_bit_cast(float, u);
}
__device__ __forceinline__ unsigned pack2(float lo, float hi) {
  return (unsigned)f2bf(lo) | ((unsigned)f2bf(hi) << 16);
}

// K1: blocks 0..511 clear bitmap; 512..639 W_fc -> B^T bf16 (32x32 tile transpose)
__global__ __launch_bounds__(256) void prep_k(const float* __restrict__ B,
                                              unsigned* __restrict__ bitmap,
                                              unsigned short* __restrict__ Btbf) {
  __shared__ float tile[32][33];
  const int b = blockIdx.x, t = threadIdx.x;
  if (b < 512) {
    ((float4*)bitmap)[b * 256 + t] = make_float4(0.f, 0.f, 0.f, 0.f);
  } else {
    int bb = b - 512;
    int k0 = (bb >> 3) * 32, n0 = (bb & 7) * 32;
    int lr = t >> 3, lc = (t & 7) * 4;
    float4 v = *(const float4*)&B[(size_t)(k0 + lr) * HF + n0 + lc];
    tile[lr][lc] = v.x; tile[lr][lc + 1] = v.y; tile[lr][lc + 2] = v.z; tile[lr][lc + 3] = v.w;
    __syncthreads();
    ushort4 o;
    o.x = f2bf(tile[lc + 0][lr]); o.y = f2bf(tile[lc + 1][lr]);
    o.z = f2bf(tile[lc + 2][lr]); o.w = f2bf(tile[lc + 3][lr]);
    *(ushort4*)&Btbf[(size_t)(n0 + lr) * KIN + k0 + lc] = o;
  }
}

// K2: blocks 0..1023 = 32x32 MFMA GEMM tiles (128 M x 8 heads), BK=64, dbuf,
//     A reg-staged straight from h (f32->bf16 in-kernel), B via global_load_lds;
//     fused el/er epilogue. Blocks 1024..1551 = build_adj.
__global__ __launch_bounds__(256) void gemm_adj_k(const float* __restrict__ h,
                                                  const unsigned short* __restrict__ Bt,
                                                  const float* __restrict__ Wa,
                                                  unsigned short* __restrict__ gbf,
                                                  float* __restrict__ el,
                                                  float* __restrict__ er,
                                                  const int* __restrict__ ei,
                                                  const float* __restrict__ mask,
                                                  unsigned* __restrict__ bitmap) {
  __shared__ unsigned short smem[2][4096];  // per buf: A[32][64]@0, B[32][64]@2048
  const int bx = blockIdx.x, t = threadIdx.x;
  if (bx >= 1024) {  // ---- build_adj: NE+NN = 135168 = 528*256 exactly ----
    int k = (bx - 1024) * 256 + t;
    int s, d; float m;
    if (k < NE) { s = ei[k]; d = ei[NE + k]; m = mask[k]; }
    else        { s = k - NE; d = s; m = 1.0f; }   // diagonal forced to 1
    if (m != 0.0f) atomicOr(&bitmap[s * 128 + (d >> 5)], 1u << (d & 31));
    return;
  }
  // ---- gemm: 32x32 tile, gy selects the head ----
  const int gx = bx & 127, gy = bx >> 7;
  const int row0 = gx * 32, col0 = gy * 32;
  const int w = t >> 6, l = t & 63;
  const int wr = w >> 1, wc = w & 1;

  const int srow = (w << 3) + (l >> 3);      // wave w stages rows 8w..8w+7
  const int sc   = l & 7;                    // linear k-chunk for A (swizzle on ds_write)
  const int aoff = srow * 64 + ((sc ^ (srow & 7)) << 3);   // swizzled LDS slot (ushorts)
  const float* gA = &h[(size_t)(row0 + srow) * KIN + sc * 8];
  const int schB = sc ^ (srow & 7);          // B source pre-swizzled (rule #21)
  const unsigned short* gB = &Bt[(size_t)(col0 + srow) * KIN + schB * 8];

#define BSTAGE(bf, ks)                                                                            \
  __builtin_amdgcn_global_load_lds(                                                               \
      (const __attribute__((address_space(1))) unsigned int*)(gB + (size_t)(ks) * 64),            \
      (__attribute__((address_space(3))) unsigned int*)(&smem[bf][2048 + w * 512]), 16, 0, 0)

  f32x4 acc = {};
  {
    float4 va0 = *(const float4*)(gA);
    float4 va1 = *(const float4*)(gA + 4);
    BSTAGE(0, 0);
    uint4 w4 = {pack2(va0.x, va0.y), pack2(va0.z, va0.w),
                pack2(va1.x, va1.y), pack2(va1.z, va1.w)};
    *(uint4*)&smem[0][aoff] = w4;
  }
  __syncthreads();

  const int lrow = l & 15, kg = l >> 4;
  const int ar = wr * 16 + lrow, br = wc * 16 + lrow;
  for (int ks = 0; ks < 8; ++ks) {
    const int bf = ks & 1;
    float4 na0, na1;
    if (ks < 7) {                            // issue next-step A loads early (T14)
      na0 = *(const float4*)(gA + (ks + 1) * 64);
      na1 = *(const float4*)(gA + (ks + 1) * 64 + 4);
      BSTAGE(bf ^ 1, ks + 1);
    }
    bf16x8 a0 = *(const bf16x8*)&smem[bf][ar * 64 + ((kg ^ (ar & 7)) << 3)];
    bf16x8 a1 = *(const bf16x8*)&smem[bf][ar * 64 + (((4 + kg) ^ (ar & 7)) << 3)];
    bf16x8 b0 = *(const bf16x8*)&smem[bf][2048 + br * 64 + ((kg ^ (br & 7)) << 3)];
    bf16x8 b1 = *(const bf16x8*)&smem[bf][2048 + br * 64 + (((4 + kg) ^ (br & 7)) << 3)];
    acc = __builtin_amdgcn_mfma_f32_16x16x32_bf16(a0, b0, acc, 0, 0, 0);
    acc = __builtin_amdgcn_mfma_f32_16x16x32_bf16(a1, b1, acc, 0, 0, 0);
    if (ks < 7) {                            // write-late into the other buffer
      uint4 w4 = {pack2(na0.x, na0.y), pack2(na0.z, na0.w),
                  pack2(na1.x, na1.y), pack2(na1.z, na1.w)};
      *(uint4*)&smem[bf ^ 1][aoff] = w4;
    }
    __syncthreads();
  }
#undef BSTAGE

  // C/D: col=lane&15, row=(lane>>4)*4+q  [m89-verified]
  const int crow = (l >> 4) * 4, ccol = l & 15;
  const int gr0 = row0 + wr * 16 + crow, gc = col0 + wc * 16 + ccol;
#pragma unroll
  for (int q = 0; q < 4; ++q) gbf[(size_t)(gr0 + q) * HF + gc] = f2bf(acc[q]);

  // fused el/er: this block's 32 cols == head gy's full f range
  float* red = (float*)smem;                 // reuse after final K-loop sync
  const int f = wc * 16 + ccol;
  const float wal = Wa[f], war = Wa[32 + f];
#pragma unroll
  for (int q = 0; q < 4; ++q) {
    float pel = acc[q] * wal, per = acc[q] * war;
#pragma unroll
    for (int m = 8; m >= 1; m >>= 1) { pel += __shfl_xor(pel, m); per += __shfl_xor(per, m); }
    if (ccol == 0) {
      int rl = wr * 16 + crow + q;
      red[wc * 32 + rl] = pel;
      red[64 + wc * 32 + rl] = per;
    }
  }
  __syncthreads();
  if (t < 32) {
    el[(row0 + t) * NH + gy] = red[t] + red[32 + t];
    er[(row0 + t) * NH + gy] = red[64 + t] + red[96 + t];
  }
}

// K3: one WAVE per row (4 rows/block, 1024 blocks). Lane l owns output elems
// [l*4, l*4+4) (all in head l>>3). Wave-local bitmap expand, no per-chunk syncs.
// No max-subtraction: |e| small -> exp f32-safe; softmax shift-invariant.
__global__ __launch_bounds__(256) void attn_k(const unsigned* __restrict__ bitmap,
                                              const unsigned short* __restrict__ gbf,
                                              const float* __restrict__ el_,
                                              const float* __restrict__ er_,
                                              float* __restrict__ out) {
  __shared__ unsigned short jl[4][NN];       // 32 KB
  const int t = threadIdx.x, wv = t >> 6, l = t & 63;
  const int i = blockIdx.x * 4 + wv;

  unsigned w0 = bitmap[i * 128 + l];
  unsigned w1 = bitmap[i * 128 + 64 + l];
  int cnt = __popc(w0) + __popc(w1);
  int incl = cnt;
#pragma unroll
  for (int d = 1; d < 64; d <<= 1) {
    int u = __shfl_up(incl, d);
    if (l >= d) incl += u;
  }
  const int total = __shfl(incl, 63);
  int off = incl - cnt;
  unsigned short* J = jl[wv];
  while (w0) { int b = __ffs(w0) - 1; J[off++] = (unsigned short)(l * 32 + b); w0 &= w0 - 1; }
  while (w1) { int b = __ffs(w1) - 1; J[off++] = (unsigned short)((64 + l) * 32 + b); w1 &= w1 - 1; }
  __syncthreads();

  const int hh = l >> 3;
  const float elh = el_[i * NH + hh];
  const unsigned short* gp = gbf + (size_t)l * 4;
  f32x4 acc = {};
  float den = 0.f;
#pragma unroll 2
  for (int k = 0; k < total; ++k) {
    int j = J[k];                            // LDS broadcast
    float e  = elh + er_[j * NH + hh];
    float lr = e > 0.f ? e : SLOPE * e;
    float wg = __expf(lr);
    ushort4 gv = *(const ushort4*)(gp + (size_t)j * HF);
    den += wg;
    acc[0] += wg * bf2f(gv.x);
    acc[1] += wg * bf2f(gv.y);
    acc[2] += wg * bf2f(gv.z);
    acc[3] += wg * bf2f(gv.w);
  }
  float inv = 1.f / den;
  float4 o = make_float4(acc[0] * inv, acc[1] * inv, acc[2] * inv, acc[3] * inv);
  *(float4*)&out[(size_t)i * HF + l * 4] = o;
}

extern "C" void kernel_launch(void* const* d_in, const int* in_sizes, int n_in,
                              void* d_out, int out_size, void* d_ws, size_t ws_size,
                              hipStream_t stream) {
  const float* h      = (const float*)d_in[0];
  const int*   ei     = (const int*)d_in[1];
  const float* mask   = (const float*)d_in[2];
  const float* W_fc   = (const float*)d_in[3];
  const float* W_attn = (const float*)d_in[4];
  float* out = (float*)d_out;

  char* ws = (char*)d_ws;
  unsigned* bitmap      = (unsigned*)ws;                                          // 2 MB
  unsigned short* gbf   = (unsigned short*)(ws + (size_t)2 * 1024 * 1024);        // 2 MB
  float* el             = (float*)(ws + (size_t)4 * 1024 * 1024);                 // 128 KB
  float* er             = (float*)(ws + (size_t)4 * 1024 * 1024 + 128 * 1024);    // 128 KB
  unsigned short* Btbf  = (unsigned short*)(ws + (size_t)4 * 1024 * 1024 + 256 * 1024);  // 256 KB

  prep_k<<<640, 256, 0, stream>>>(W_fc, bitmap, Btbf);
  gemm_adj_k<<<1024 + 528, 256, 0, stream>>>(h, Btbf, W_attn, gbf, el, er, ei, mask, bitmap);
  attn_k<<<NN / 4, 256, 0, stream>>>(bitmap, gbf, el, er, out);
}